// Round 12
// baseline (8724.158 us; speedup 1.0000x reference)
//
#include <hip/hip_runtime.h>
#include <hip/hip_bf16.h>

typedef unsigned short ushort_t;
typedef unsigned int   uint_t;

// Problem constants: T1=257, B=512, SD=128, AD=32, HS=512, SF=256, L=2
#define M_ALL 131584   // 257*512
#define M_SEQ 131072   // 256*512

// ---------- helpers ----------
__device__ __forceinline__ float bf2f(ushort_t u) {
    union { uint_t i; float f; } v; v.i = ((uint_t)u) << 16; return v.f;
}
__device__ __forceinline__ float asf(uint_t i) {
    union { uint_t u; float f; } v; v.u = i; return v.f;
}
__device__ __forceinline__ ushort_t f2bf(float f) {
    union { float f; uint_t i; } v; v.f = f;
    uint_t r = v.i + 0x7FFFu + ((v.i >> 16) & 1u);
    return (ushort_t)(r >> 16);
}
__device__ __forceinline__ float fsigm(float x) { return 1.f / (1.f + __expf(-x)); }
__device__ __forceinline__ float ftanh(float x) {
    x = fminf(15.f, fmaxf(-15.f, x));
    float e = __expf(2.f * x);
    return (e - 1.f) / (e + 1.f);
}

typedef __attribute__((ext_vector_type(8))) short  bfrag;   // 8 x bf16
typedef __attribute__((ext_vector_type(4))) float  ffrag;   // 4 x f32 accum

// ---------- staging registers (prefetch double-buffer) ----------
template<typename T> struct StReg;
template<> struct StReg<ushort_t> { uint4 v; };
template<> struct StReg<float>    { float4 a, b; };

__device__ __forceinline__ void ldreg(StReg<ushort_t>& r, const ushort_t* p) {
    r.v = *(const uint4*)p;
}
__device__ __forceinline__ void ldreg(StReg<float>& r, const float* p) {
    r.a = *(const float4*)p; r.b = *(const float4*)(p + 4);
}
__device__ __forceinline__ void streg(const StReg<ushort_t>& r, ushort_t* d) {
    *(uint4*)d = r.v;
}
__device__ __forceinline__ void streg(const StReg<float>& r, ushort_t* d) {
    bfrag v;
    v[0] = (short)f2bf(r.a.x); v[1] = (short)f2bf(r.a.y);
    v[2] = (short)f2bf(r.a.z); v[3] = (short)f2bf(r.a.w);
    v[4] = (short)f2bf(r.b.x); v[5] = (short)f2bf(r.b.y);
    v[6] = (short)f2bf(r.b.z); v[7] = (short)f2bf(r.b.w);
    *(bfrag*)d = v;
}

template<typename TA1, typename TA2> struct StA { StReg<TA1> r1; StReg<TA2> r2; int use2; };

template<int AMODE, typename TA1, typename TA2>
__device__ __forceinline__ void load_a(StA<TA1, TA2>& s, const TA1* A1, const TA2* A2,
                                       int m, int kk, int K) {
    if (AMODE == 0) {
        ldreg(s.r1, A1 + (size_t)m * K + kk); s.use2 = 0;
    } else if (AMODE == 1) {
        if (kk < 256) { ldreg(s.r1, A1 + (size_t)m * 256 + kk); s.use2 = 0; }
        else          { ldreg(s.r2, A2 + (size_t)m * 32 + (kk - 256)); s.use2 = 1; }
    } else {
        if (kk < 256) { ldreg(s.r1, A1 + (size_t)m * 256 + kk); s.use2 = 0; }
        else          { ldreg(s.r2, A2 + (size_t)m * 256 + (kk - 256)); s.use2 = 1; }
    }
}
template<typename TA1, typename TA2>
__device__ __forceinline__ void st_a(const StA<TA1, TA2>& s, ushort_t* d) {
    if (!s.use2) streg(s.r1, d); else streg(s.r2, d);
}

// ---------- 128x128-tile bf16 MFMA GEMM with register-prefetch staging ----------
// C = act(A @ W^T + bias). Prologue loads K-tile 0 into VGPRs; each iteration stores
// regs->LDS, barriers, then ISSUES tile k+1's global loads before the MFMAs so the
// load latency overlaps ds_read+MFMA (the K-loops here are only 4-16 iterations, so
// without prefetch every iteration pays the full global-load latency).
template<int AMODE, int ACT, typename TA1, typename TA2>
__device__ __forceinline__ void gemm_body(
    const TA1* __restrict__ A1, const TA2* __restrict__ A2,
    const ushort_t* __restrict__ W, const float* __restrict__ b1,
    ushort_t* __restrict__ C, int K, int N)
{
    __shared__ __align__(16) ushort_t As[128][40];
    __shared__ __align__(16) ushort_t Ws[128][40];

    const int tid  = threadIdx.x;
    const int m0   = blockIdx.x * 128;
    const int n0   = blockIdx.y * 128;
    const int lane = tid & 63;
    const int wv   = tid >> 6;
    const int wm   = (wv & 1) * 64;
    const int wn   = (wv >> 1) * 64;
    const int quad = lane >> 4;
    const int ln   = lane & 15;

    ffrag acc[4][4];
#pragma unroll
    for (int i = 0; i < 4; i++)
#pragma unroll
        for (int j = 0; j < 4; j++) acc[i][j] = (ffrag){0.f, 0.f, 0.f, 0.f};

    const int arow = tid >> 2;        // 0..63 (stages rows arow, arow+64)
    const int acol = (tid & 3) * 8;   // 0,8,16,24

    StA<TA1, TA2> sa[2];
    StReg<ushort_t> sw[2];
#pragma unroll
    for (int rr = 0; rr < 2; rr++) {
        load_a<AMODE>(sa[rr], A1, A2, m0 + arow + rr * 64, acol, K);
        ldreg(sw[rr], W + (size_t)(n0 + arow + rr * 64) * K + acol);
    }

    for (int k0 = 0; k0 < K; k0 += 32) {
#pragma unroll
        for (int rr = 0; rr < 2; rr++) {
            st_a(sa[rr], &As[arow + rr * 64][acol]);
            streg(sw[rr], &Ws[arow + rr * 64][acol]);
        }
        __syncthreads();

        if (k0 + 32 < K) {            // issue next tile's loads NOW (consumed next iter)
            const int kk = k0 + 32 + acol;
#pragma unroll
            for (int rr = 0; rr < 2; rr++) {
                load_a<AMODE>(sa[rr], A1, A2, m0 + arow + rr * 64, kk, K);
                ldreg(sw[rr], W + (size_t)(n0 + arow + rr * 64) * K + kk);
            }
        }

        bfrag af[4], bfv[4];
#pragma unroll
        for (int i = 0; i < 4; i++) af[i]  = *(const bfrag*)&As[wm + i * 16 + ln][quad * 8];
#pragma unroll
        for (int j = 0; j < 4; j++) bfv[j] = *(const bfrag*)&Ws[wn + j * 16 + ln][quad * 8];
#pragma unroll
        for (int i = 0; i < 4; i++)
#pragma unroll
            for (int j = 0; j < 4; j++)
                acc[i][j] = __builtin_amdgcn_mfma_f32_16x16x32_bf16(af[i], bfv[j], acc[i][j], 0, 0, 0);
        __syncthreads();
    }

#pragma unroll
    for (int j = 0; j < 4; j++) {
        const int n = n0 + wn + j * 16 + ln;
        const float bias = b1[n];
#pragma unroll
        for (int i = 0; i < 4; i++) {
#pragma unroll
            for (int r = 0; r < 4; r++) {
                const int m = m0 + wm + i * 16 + quad * 4 + r;
                float x = acc[i][j][r] + bias;
                if (ACT == 1) x = fmaxf(x, 0.f);
                C[(size_t)m * N + n] = f2bf(x);
            }
        }
    }
}

// Distinct kernel names per GEMM site => per-GEMM visibility in rocprof top-k.
#define GEMM_KERNEL(NAME, AMODE, ACT, TA1, TA2) \
__global__ __launch_bounds__(256) void NAME( \
    const TA1* __restrict__ A1, const TA2* __restrict__ A2, \
    const ushort_t* __restrict__ W, const float* __restrict__ b1, \
    ushort_t* __restrict__ C, int K, int N) \
{ gemm_body<AMODE, ACT, TA1, TA2>(A1, A2, W, b1, C, K, N); }

GEMM_KERNEL(g_feats, 0, 1, float,    float)
GEMM_KERNEL(g_xg0,   0, 0, ushort_t, ushort_t)
GEMM_KERNEL(g_xg1,   0, 0, ushort_t, ushort_t)
GEMM_KERNEL(g_ph,    1, 1, ushort_t, float)
GEMM_KERNEL(g_pn,    0, 0, ushort_t, ushort_t)
GEMM_KERNEL(g_msh,   2, 1, ushort_t, ushort_t)

// ---------- prep: bf16 weights + gate-interleaved recurrent layouts ----------
struct PrepArgs {
    const float *Wfe, *Wih0, *Whh0, *bih0, *bhh0, *Wih1, *Whh1, *bih1, *bhh1;
    const float *Wf1, *Wf2, *Wm1, *Ws1, *Wm2, *Ws2;
    const float *bm1, *bs1;
    ushort_t *Wfe_b, *Wih0_b, *Wih1_b, *wt0, *wt1, *Wf1_b, *Wf2_b, *Wms_b;
    float *W2t, *bias0s, *bias1s, *bms;
};
__global__ __launch_bounds__(256) void prep_k(PrepArgs a)
{
    const int idx = blockIdx.x * 256 + threadIdx.x;
    const int stride = gridDim.x * 256;
    for (int e = idx; e < 65536; e += stride)  a.Wfe_b[e]  = f2bf(a.Wfe[e]);
    for (int e = idx; e < 524288; e += stride) a.Wih0_b[e] = f2bf(a.Wih0[e]);   // (1024,512)
    for (int e = idx; e < 262144; e += stride) a.Wih1_b[e] = f2bf(a.Wih1[e]);   // (1024,256)
    for (int e = idx; e < 262144; e += stride) {              // wt0
        const int k = e >> 10, q = e & 1023;
        const int s = q & 1, u = (q >> 1) & 255;
        const int j = ((q >> 9) << 9) + s * 256 + u;
        a.wt0[e] = f2bf(a.Whh0[j * 256 + k]);
    }
    for (int e = idx; e < 524288; e += stride) {              // wt1 (upper half = Whh1 interleave)
        const int k = e >> 10, q = e & 1023;
        const int s = q & 1, u = (q >> 1) & 255;
        const int j = ((q >> 9) << 9) + s * 256 + u;
        a.wt1[e] = f2bf((k < 256) ? a.Wih1[j * 256 + k] : a.Whh1[j * 256 + (k - 256)]);
    }
    for (int e = idx; e < 147456; e += stride) a.Wf1_b[e] = f2bf(a.Wf1[e]);
    for (int e = idx; e < 131072; e += stride) a.Wf2_b[e] = f2bf(a.Wf2[e]);
    for (int e = idx; e < 524288; e += stride) {              // Wms_b: (1024,512) = [Wm1; Ws1]
        const int n = e >> 9, k = e & 511;
        a.Wms_b[e] = f2bf((n < 512) ? a.Wm1[n * 512 + k] : a.Ws1[(n - 512) * 512 + k]);
    }
    for (int e = idx; e < 32768; e += stride) {               // W2t: (512,64) k-major f32
        const int k = e >> 6, c = e & 63;
        a.W2t[e] = (c < 32) ? a.Wm2[c * 512 + k] : a.Ws2[(c - 32) * 512 + k];
    }
    for (int e = idx; e < 1024; e += stride) {
        a.bias0s[e] = a.bih0[e] + a.bhh0[e];
        a.bias1s[e] = a.bih1[e] + a.bhh1[e];
        a.bms[e]    = (e < 512) ? a.bm1[e] : a.bs1[e - 512];
    }
}

// ---------- block-local LSTM scan (NO grid sync): one layer, 256 indep blocks ----------
struct ScanArgs {
    const ushort_t* xg;      // (nsteps*512, 1024) bf16, gate order {i,f,g,o}x256
    const int*      dones;   // (257,512) int32, absolute t indexing
    const ushort_t* wt;      // gate-interleaved recurrent weights (256 k-rows, 1024)
    ushort_t*       hout;    // bf16 h stream: (nsteps*512, 256), chunk-local s indexing
    float*          hst;     // persistent h (512*256 f32)
    float*          cst;     // persistent c (512*256 f32)
    int jc, nsteps, init;
};

__global__ __launch_bounds__(512) void scan_k(ScanArgs a)
{
    __shared__ __align__(16) float xs[2][264];
    const int tid = threadIdx.x;
    const int row = tid >> 8, u = tid & 255;
    const int b = blockIdx.x * 2 + row;
    float h = a.init ? 0.f : a.hst[b * 256 + u];
    float c = a.init ? 0.f : a.cst[b * 256 + u];
    const ushort_t* wtu = a.wt + 2 * u;

    for (int sst = 0; sst < a.nsteps; ++sst) {
        const int t = a.jc + sst;
        const float m = 1.f - (float)a.dones[t * 512 + b];
        xs[row][u] = h * m;
        __syncthreads();
        const size_t base = ((size_t)sst * 512 + b) * 1024;
        float ai = bf2f(a.xg[base + u]),       af = bf2f(a.xg[base + 256 + u]);
        float ag = bf2f(a.xg[base + 512 + u]), ao = bf2f(a.xg[base + 768 + u]);
        for (int k0 = 0; k0 < 256; k0 += 8) {
            uint_t pif[8], pgo[8];
#pragma unroll
            for (int e = 0; e < 8; e++) {
                pif[e] = *(const uint_t*)(wtu + ((k0 + e) << 10));
                pgo[e] = *(const uint_t*)(wtu + ((k0 + e) << 10) + 512);
            }
            float hr[8];
            *(float4*)&hr[0] = *(const float4*)&xs[row][k0];
            *(float4*)&hr[4] = *(const float4*)&xs[row][k0 + 4];
#pragma unroll
            for (int e = 0; e < 8; e++) {
                const float wi = asf(pif[e] << 16), wf = asf(pif[e] & 0xFFFF0000u);
                const float wg = asf(pgo[e] << 16), wo = asf(pgo[e] & 0xFFFF0000u);
                ai += hr[e] * wi; af += hr[e] * wf; ag += hr[e] * wg; ao += hr[e] * wo;
            }
        }
        const float cold = c * m;
        const float c2 = fsigm(af) * cold + fsigm(ai) * ftanh(ag);
        const float h2 = fsigm(ao) * ftanh(c2);
        c = c2; h = h2;
        a.hout[((size_t)sst * 512 + b) * 256 + u] = f2bf(h2);
        __syncthreads();
    }
    a.hst[b * 256 + u] = h;
    a.cst[b * 256 + u] = c;
}

// ---------- forward loss + intrinsic reward (row-chunked), f32 out ----------
__global__ __launch_bounds__(256) void fl_k(const ushort_t* __restrict__ pn,
                                            const ushort_t* __restrict__ outs,
                                            float* __restrict__ out, float* __restrict__ acc,
                                            int r0, int out_size)
{
    __shared__ float bs[4];
    const int tid = threadIdx.x;
    const int w = tid >> 6, l = tid & 63;
    const size_t rl = (size_t)blockIdx.x * 4 + w;
    const size_t rg = rl + r0;
    const ushort_t* p = pn + rl * 256;
    const ushort_t* q = outs + (rg + 512) * 256;   // next_state_features = outs[t+1]
    float s = 0.f;
#pragma unroll
    for (int i = 0; i < 4; i++) {
        const float d = bf2f(p[l + i * 64]) - bf2f(q[l + i * 64]);
        s += d * d;
    }
#pragma unroll
    for (int off = 32; off > 0; off >>= 1) s += __shfl_down(s, off);
    if (l == 0) { if ((long long)(2 + rg) < out_size) out[2 + rg] = s; bs[w] = s; }
    __syncthreads();
    if (tid == 0) atomicAdd(acc, bs[0] + bs[1] + bs[2] + bs[3]);
}

// ---------- fused mu/std heads + inverse loss (row-chunked), packed msh ----------
__global__ __launch_bounds__(256) void musd_k(
    const ushort_t* __restrict__ msh,    // (rows, 1024): [mh | sh]
    const float* __restrict__ W2t, const float* __restrict__ bm2,
    const float* __restrict__ bs2, const float* __restrict__ action,
    float* __restrict__ acc, int r0)
{
    __shared__ __align__(16) ushort_t mhs[8][512];
    __shared__ __align__(16) ushort_t shs[8][512];
    __shared__ float red[256];
    const int tid = threadIdx.x;
    const size_t rl0 = (size_t)blockIdx.x * 8;
    for (int i = tid; i < 512; i += 256) {
        const int row = i >> 6, c = (i & 63) * 8;
        *(uint4*)&mhs[row][c] = *(const uint4*)&msh[(rl0 + row) * 1024 + c];
        *(uint4*)&shs[row][c] = *(const uint4*)&msh[(rl0 + row) * 1024 + 512 + c];
    }
    __syncthreads();
    const int row = tid >> 5, c = tid & 31;
    float am = bm2[c], asv = bs2[c];
    for (int k = 0; k < 512; k += 8) {
#pragma unroll
        for (int e = 0; e < 8; e++) {
            const float wm = W2t[(k + e) * 64 + c];
            const float wsv = W2t[(k + e) * 64 + 32 + c];
            am  += bf2f(mhs[row][k + e]) * wm;
            asv += bf2f(shs[row][k + e]) * wsv;
        }
    }
    const float mu = ftanh(am);
    const float sp = fmaxf(asv, 0.f) + log1pf(__expf(-fabsf(asv)));   // softplus
    const float a  = action[(rl0 + r0 + row) * 32 + c];
    const float z  = (a - mu) / sp;
    red[tid] = 0.5f * z * z + __logf(sp) + 0.918938533204672741f;     // -log_prob
    __syncthreads();
    for (int s = 128; s > 0; s >>= 1) { if (tid < s) red[tid] += red[tid + s]; __syncthreads(); }
    if (tid == 0) atomicAdd(acc, red[0]);
}

// ---------- finalize: scalar losses + hidden copy-out (f32) ----------
__global__ __launch_bounds__(256) void fin_k(const float* __restrict__ acc,
                                             const float* __restrict__ h0st,
                                             const float* __restrict__ h1st,
                                             const float* __restrict__ c0st,
                                             const float* __restrict__ c1st,
                                             float* __restrict__ out, int out_size)
{
    const size_t idx = (size_t)blockIdx.x * 256 + threadIdx.x;
    if (idx == 0 && out_size > 0) out[0] = acc[0] / 33554432.f;   // mean over 256*512*256
    if (idx == 1 && out_size > 1) out[1] = acc[1] / 4194304.f;    // mean over 256*512*32
    if (idx < 524288) {
        const int which = (int)(idx >> 17);
        const int local = (int)(idx & 131071);
        float v;
        if      (which == 0) v = h0st[local];
        else if (which == 1) v = h1st[local];
        else if (which == 2) v = c0st[local];
        else                 v = c1st[local];
        const size_t o = 2 + 131072 + idx;
        if ((long long)o < out_size) out[o] = v;
    }
}

extern "C" void kernel_launch(void* const* d_in, const int* in_sizes, int n_in,
                              void* d_out, int out_size, void* d_ws, size_t ws_size,
                              hipStream_t stream)
{
    const float* states = (const float*)d_in[0];
    const float* action = (const float*)d_in[1];
    const int*   dones  = (const int*)d_in[2];
    const float* Wfe  = (const float*)d_in[3];
    const float* bfe  = (const float*)d_in[4];
    const float* Wih0 = (const float*)d_in[5];
    const float* Whh0 = (const float*)d_in[6];
    const float* bih0 = (const float*)d_in[7];
    const float* bhh0 = (const float*)d_in[8];
    const float* Wih1 = (const float*)d_in[9];
    const float* Whh1 = (const float*)d_in[10];
    const float* bih1 = (const float*)d_in[11];
    const float* bhh1 = (const float*)d_in[12];
    const float* Wf1  = (const float*)d_in[13];
    const float* bf1  = (const float*)d_in[14];
    const float* Wf2  = (const float*)d_in[15];
    const float* bf2  = (const float*)d_in[16];
    const float* Wm1  = (const float*)d_in[17];
    const float* bm1  = (const float*)d_in[18];
    const float* Wm2  = (const float*)d_in[19];
    const float* bm2  = (const float*)d_in[20];
    const float* Ws1  = (const float*)d_in[21];
    const float* bs1  = (const float*)d_in[22];
    const float* Ws2  = (const float*)d_in[23];
    const float* bs2  = (const float*)d_in[24];

    // ---------- workspace layout (persistent region) ----------
    char* ws = (char*)d_ws;
    size_t off = 0;
    ushort_t* outs    = (ushort_t*)(ws + off); off += 67371008;  // 257*512*256 bf16
    float*    h0st    = (float*)(ws + off);    off += 524288;
    float*    c0st    = (float*)(ws + off);    off += 524288;
    float*    h1st    = (float*)(ws + off);    off += 524288;
    float*    c1st    = (float*)(ws + off);    off += 524288;
    ushort_t* wt0     = (ushort_t*)(ws + off); off += 524288;
    ushort_t* wt1     = (ushort_t*)(ws + off); off += 1048576;
    ushort_t* Wfe_b   = (ushort_t*)(ws + off); off += 131072;
    ushort_t* Wih0_b  = (ushort_t*)(ws + off); off += 1048576;
    ushort_t* Wih1_b  = (ushort_t*)(ws + off); off += 524288;
    ushort_t* Wf1_b   = (ushort_t*)(ws + off); off += 294912;
    ushort_t* Wf2_b   = (ushort_t*)(ws + off); off += 262144;
    ushort_t* Wms_b   = (ushort_t*)(ws + off); off += 1048576;
    float*    W2t     = (float*)(ws + off);    off += 131072;
    float*    bias0s  = (float*)(ws + off);    off += 4096;
    float*    bias1s  = (float*)(ws + off);    off += 4096;
    float*    bms     = (float*)(ws + off);    off += 4096;
    float*    accp    = (float*)(ws + off);    off += 256;
    char*     S       = ws + off;              // chunk scratch
    const size_t avail = (ws_size > off) ? (ws_size - off) : 0;

    // scan-phase chunk: feats 524288 + xg0 1048576 + h0s 262144 + xg1 1048576 B per step.
    const size_t STEP_B = 2883584;
    int TC = (int)(avail / STEP_B);
    if (TC > 257) TC = 257;
    if (TC < 1)  TC = 1;
    // head-phase chunk: per row ph(1024)+pn(512)+msh(2048) = 3584 B; cap 24576 rows (~88 MB L3-resident).
    long long rc = (long long)(avail / 3584) & ~127LL;
    if (rc > 24576) rc = 24576;
    if (rc < 128)   rc = 128;
    const int RC = (int)rc;

    hipMemsetAsync(accp, 0, 256, stream);

    PrepArgs pa{ Wfe, Wih0, Whh0, bih0, bhh0, Wih1, Whh1, bih1, bhh1,
                 Wf1, Wf2, Wm1, Ws1, Wm2, Ws2, bm1, bs1,
                 Wfe_b, Wih0_b, Wih1_b, wt0, wt1, Wf1_b, Wf2_b, Wms_b,
                 W2t, bias0s, bias1s, bms };
    prep_k<<<512, 256, 0, stream>>>(pa);

    // ---------- scan phase ----------
    ushort_t* featsck = (ushort_t*)S;
    ushort_t* xg0ck   = (ushort_t*)(S + (size_t)TC * 524288);
    ushort_t* h0sck   = (ushort_t*)(S + (size_t)TC * 1572864);
    ushort_t* xg1ck   = (ushort_t*)(S + (size_t)TC * 1835008);
    for (int jc = 0; jc < 257; jc += TC) {
        const int nsteps = (257 - jc < TC) ? (257 - jc) : TC;
        // feats = relu(states_chunk @ Wfe^T + bfe)      [N=512, K=128]
        g_feats<<<dim3(nsteps * 4, 4), 256, 0, stream>>>(
            states + (size_t)jc * 512 * 128, nullptr, Wfe_b, bfe, featsck, 128, 512);
        // xg0 = feats @ Wih0^T + (bih0 + bhh0)          [N=1024, K=512]
        g_xg0<<<dim3(nsteps * 4, 8), 256, 0, stream>>>(
            featsck, nullptr, Wih0_b, bias0s, xg0ck, 512, 1024);
        // layer-0 scan
        ScanArgs sa0{ xg0ck, dones, wt0, h0sck, h0st, c0st, jc, nsteps, (jc == 0) ? 1 : 0 };
        scan_k<<<256, 512, 0, stream>>>(sa0);
        // xg1 = h0s @ Wih1^T + (bih1 + bhh1)            [N=1024, K=256]
        g_xg1<<<dim3(nsteps * 4, 8), 256, 0, stream>>>(
            h0sck, nullptr, Wih1_b, bias1s, xg1ck, 256, 1024);
        // layer-1 scan
        ScanArgs sa1{ xg1ck, dones, wt1 + 262144, outs + (size_t)jc * 131072,
                      h1st, c1st, jc, nsteps, (jc == 0) ? 1 : 0 };
        scan_k<<<256, 512, 0, stream>>>(sa1);
    }

    // ---------- head phase (row-chunked, L3-resident chunks) ----------
    for (int r0 = 0; r0 < M_SEQ; r0 += RC) {
        const int rows = (M_SEQ - r0 < RC) ? (M_SEQ - r0) : RC;
        ushort_t* ph  = (ushort_t*)S;
        ushort_t* pn  = (ushort_t*)(S + (size_t)rows * 1024);
        ushort_t* msh = (ushort_t*)(S + (size_t)rows * 1536);
        // pred_hidden = relu([sf, action] @ Wf1^T + bf1)  [N=512, K=288]
        g_ph<<<dim3(rows / 128, 4), 256, 0, stream>>>(
            outs + (size_t)r0 * 256, action + (size_t)r0 * 32, Wf1_b, bf1, ph, 288, 512);
        // pred_next = pred_hidden @ Wf2^T + bf2           [N=256, K=512]
        g_pn<<<dim3(rows / 128, 2), 256, 0, stream>>>(
            ph, nullptr, Wf2_b, bf2, pn, 512, 256);
        // forward loss + intrinsic reward
        fl_k<<<rows / 4, 256, 0, stream>>>(pn, outs, (float*)d_out, accp, r0, out_size);
        // msh = relu([sf, pred_next] @ [Wm1;Ws1]^T + [bm1;bs1])  [N=1024, K=512]
        g_msh<<<dim3(rows / 128, 8), 256, 0, stream>>>(
            outs + (size_t)r0 * 256, pn, Wms_b, bms, msh, 512, 1024);
        // mu/std heads + inverse loss
        musd_k<<<rows / 8, 256, 0, stream>>>(msh, W2t, bm2, bs2, action, accp + 1, r0);
    }

    // scalars + hidden
    fin_k<<<2048, 256, 0, stream>>>(accp, h0st, h1st, c0st, c1st, (float*)d_out, out_size);
}